// Round 13
// baseline (488.401 us; speedup 1.0000x reference)
//
#include <hip/hip_runtime.h>

typedef unsigned int uint;
typedef __attribute__((ext_vector_type(8))) short short8;   // 8 bf16 (4 VGPRs)
typedef __attribute__((ext_vector_type(4))) float f32x4;    // MFMA accumulator

#define N_NODES 100000
#define N_EDGES 1600000
#define NB_SCAN 391          // ceil(N_NODES/256)
#define CONVG_N 1563         // ceil(N_NODES/64)
#define EB 6250              // ceil(N_EDGES/256)
#define TFG 12500            // ceil(N_NODES*32/256)

// ---------------------------------------------------------------- bf16 helpers
__device__ __forceinline__ float bflo(uint v) { return __uint_as_float(v << 16); }
__device__ __forceinline__ float bfhi(uint v) { return __uint_as_float(v & 0xffff0000u); }
__device__ __forceinline__ uint packbf2(float a, float b) {   // RNE pack (a->lo, b->hi)
    uint ua = __float_as_uint(a), ub = __float_as_uint(b);
    ua += 0x7fffu + ((ua >> 16) & 1u);
    ub += 0x7fffu + ((ub >> 16) & 1u);
    return (ua >> 16) | (ub & 0xffff0000u);
}

// ---------------------------------------------------------------- fused prep
__device__ __forceinline__ void pack_w_body(const float* __restrict__ Wself,
                                            const float* __restrict__ Wneigh,
                                            uint* __restrict__ Wb, int OUTC, int NT, int i) {
    if (i >= 8 * NT * 64 * 4) return;
    int u = i & 3;
    int l = (i >> 2) & 63;
    int t = i >> 8;            // s*NT + c
    int c = t % NT, s = t / NT;
    int k = s * 32 + (l >> 4) * 8 + u * 2;
    int col = c * 16 + (l & 15);
    const float* W0 = (k < 128) ? (Wself + (size_t)k * OUTC)
                                : (Wneigh + (size_t)(k - 128) * OUTC);
    const float* W1 = (k + 1 < 128) ? (Wself + (size_t)(k + 1) * OUTC)
                                    : (Wneigh + (size_t)(k + 1 - 128) * OUTC);
    Wb[i] = packbf2(W0[col], W1[col]);
}

__global__ void prep_fused(const int* __restrict__ dst,
                           int* __restrict__ deg, int* __restrict__ rank,
                           const float* __restrict__ x, uint* __restrict__ ht2,
                           const float* __restrict__ w0s, const float* __restrict__ w0n, uint* __restrict__ wb0,
                           const float* __restrict__ w1s, const float* __restrict__ w1n, uint* __restrict__ wb1,
                           const float* __restrict__ w2s, const float* __restrict__ w2n, uint* __restrict__ wb2) {
    int b = blockIdx.x;
    int tid = threadIdx.x;
    if (b < EB) {
        int e = b * 256 + tid;
        if (e < N_EDGES) rank[e] = atomicAdd(&deg[dst[e]], 1);
    } else if (b < EB + TFG) {
        int i = (b - EB) * 256 + tid;
        if (i < N_NODES * 32) {
            int row = i >> 5, q = i & 31;
            float4 v = *(const float4*)(x + (size_t)row * 128 + q * 4);
            uint2 o;
            o.x = packbf2(v.x, v.y);
            o.y = packbf2(v.z, v.w);
            *(uint2*)(ht2 + (size_t)row * 64 + q * 2) = o;
        }
    } else if (b < EB + TFG + 64) {
        pack_w_body(w0s, w0n, wb0, 128, 8, (b - EB - TFG) * 256 + tid);
    } else if (b < EB + TFG + 128) {
        pack_w_body(w1s, w1n, wb1, 128, 8, (b - EB - TFG - 64) * 256 + tid);
    } else {
        pack_w_body(w2s, w2n, wb2, 64, 4, (b - EB - TFG - 128) * 256 + tid);
    }
}

// ---------------------------------------------------------------- scans
__global__ void scan_blocksum(const int* __restrict__ deg, int* __restrict__ blk) {
    __shared__ int s[256];
    int i = blockIdx.x * 256 + threadIdx.x;
    s[threadIdx.x] = (i < N_NODES) ? deg[i] : 0;
    __syncthreads();
    for (int off = 128; off > 0; off >>= 1) {
        if (threadIdx.x < off) s[threadIdx.x] += s[threadIdx.x + off];
        __syncthreads();
    }
    if (threadIdx.x == 0) blk[blockIdx.x] = s[0];
}

__global__ void scan_blockoff(int* __restrict__ blk, int* __restrict__ row_ptr_last) {
    __shared__ int s[512];
    int t = threadIdx.x;
    int v = (t < NB_SCAN) ? blk[t] : 0;
    s[t] = v;
    __syncthreads();
    for (int off = 1; off < 512; off <<= 1) {
        int xv = (t >= off) ? s[t - off] : 0;
        __syncthreads();
        s[t] += xv;
        __syncthreads();
    }
    if (t < NB_SCAN) blk[t] = s[t] - v;           // exclusive
    if (t == NB_SCAN - 1) *row_ptr_last = s[t];   // total = N_EDGES
}

__global__ void scan_final(const int* __restrict__ deg, const int* __restrict__ blk,
                           int* __restrict__ row_ptr, float* __restrict__ invd) {
    __shared__ int s[256];
    int i = blockIdx.x * 256 + threadIdx.x;
    int v = (i < N_NODES) ? deg[i] : 0;
    s[threadIdx.x] = v;
    __syncthreads();
    for (int off = 1; off < 256; off <<= 1) {
        int xv = (threadIdx.x >= off) ? s[threadIdx.x - off] : 0;
        __syncthreads();
        s[threadIdx.x] += xv;
        __syncthreads();
    }
    if (i < N_NODES) {
        row_ptr[i] = blk[blockIdx.x] + s[threadIdx.x] - v;
        invd[i] = 1.0f / fmaxf((float)v, 1.0f);
    }
}

__global__ void fill_csr2(const int* __restrict__ src, const int* __restrict__ dst,
                          const int* __restrict__ row_ptr, const int* __restrict__ rank,
                          int* __restrict__ colx) {
    int e = blockIdx.x * blockDim.x + threadIdx.x;
    if (e < N_EDGES) colx[row_ptr[dst[e]] + rank[e]] = src[e];
}

// ---------------------------------------------------------------- fused aggregate+conv
// Per block (4 waves, 64 output rows):
//   phase 1: each wave gathers 16 nodes' neighbor mean (lane = channel pair,
//            unroll-8, optional on-the-fly relu(v*scale+shift)) into LDS
//            aggL[64][68] (+4-uint row pad -> conflict-free b128 frag reads).
//   phase 2: MFMA; self-A fragments from global H2 (optional TF), neighbor-A
//            fragments from aggL. Blocks interleave phases across the CU ->
//            gather (memory) overlaps MFMA (matrix pipe) chip-wide.
// NOTE: gathers RANDOM rows of H2 while producing Out -> Out must NOT alias
// H2 (hidden state is double-buffered h2a/h2b).
template <int OUTC, bool STATS, bool BF16OUT, bool TF, bool LSM>
__global__ __launch_bounds__(256) void aggconv(
    const uint* __restrict__ H2,
    const float* __restrict__ scale, const float* __restrict__ shift,
    const int* __restrict__ row_ptr, const int* __restrict__ colx,
    const float* __restrict__ invd,
    const uint* __restrict__ Wb, const float* __restrict__ bias,
    float* __restrict__ OutF, uint* __restrict__ OutB, float* __restrict__ Ppart) {
    constexpr int NT = OUTC / 16;
    __shared__ uint aggL[64][68];
    __shared__ float red[4][2 * OUTC];
    const int lane = threadIdx.x & 63;
    const int wv   = threadIdx.x >> 6;
    const int wrow0 = blockIdx.x * 64 + wv * 16;

    // ---- phase 1: gather 16 nodes per wave into LDS
    {
        float sc0 = 0.f, sc1 = 0.f, sh0 = 0.f, sh1 = 0.f;
        if (TF) {
            sc0 = scale[2 * lane];     sc1 = scale[2 * lane + 1];
            sh0 = shift[2 * lane];     sh1 = shift[2 * lane + 1];
        }
#define ACC1(v)                                                        \
        if (TF) {                                                      \
            a0 += fmaxf(bflo(v) * sc0 + sh0, 0.f);                     \
            a1 += fmaxf(bfhi(v) * sc1 + sh1, 0.f);                     \
        } else {                                                       \
            a0 += bflo(v);                                             \
            a1 += bfhi(v);                                             \
        }
        for (int i = 0; i < 16; ++i) {
            int node = wrow0 + i;
            float a0 = 0.f, a1 = 0.f;
            if (node < N_NODES) {
                int beg = row_ptr[node], end = row_ptr[node + 1];
                int j = beg;
                for (; j + 8 <= end; j += 8) {
                    int s0 = colx[j],     s1 = colx[j + 1], s2 = colx[j + 2], s3 = colx[j + 3];
                    int s4 = colx[j + 4], s5 = colx[j + 5], s6 = colx[j + 6], s7 = colx[j + 7];
                    uint v0 = H2[(size_t)s0 * 64 + lane];
                    uint v1 = H2[(size_t)s1 * 64 + lane];
                    uint v2 = H2[(size_t)s2 * 64 + lane];
                    uint v3 = H2[(size_t)s3 * 64 + lane];
                    uint v4 = H2[(size_t)s4 * 64 + lane];
                    uint v5 = H2[(size_t)s5 * 64 + lane];
                    uint v6 = H2[(size_t)s6 * 64 + lane];
                    uint v7 = H2[(size_t)s7 * 64 + lane];
                    ACC1(v0) ACC1(v1) ACC1(v2) ACC1(v3) ACC1(v4) ACC1(v5) ACC1(v6) ACC1(v7)
                }
                for (; j + 4 <= end; j += 4) {
                    int s0 = colx[j], s1 = colx[j + 1], s2 = colx[j + 2], s3 = colx[j + 3];
                    uint v0 = H2[(size_t)s0 * 64 + lane];
                    uint v1 = H2[(size_t)s1 * 64 + lane];
                    uint v2 = H2[(size_t)s2 * 64 + lane];
                    uint v3 = H2[(size_t)s3 * 64 + lane];
                    ACC1(v0) ACC1(v1) ACC1(v2) ACC1(v3)
                }
                for (; j < end; ++j) {
                    uint v = H2[(size_t)colx[j] * 64 + lane];
                    ACC1(v)
                }
                float id = invd[node];
                a0 *= id; a1 *= id;
            }
            aggL[wv * 16 + i][lane] = packbf2(a0, a1);
        }
#undef ACC1
    }
    __syncthreads();

    // ---- phase 2: MFMA
    const int arow = wrow0 + (lane & 15);
    const bool aok = arow < N_NODES;
    const int kq   = lane >> 4;      // 0..3

    f32x4 acc[NT];
#pragma unroll
    for (int c = 0; c < NT; ++c) acc[c] = (f32x4){0.f, 0.f, 0.f, 0.f};

    union U { uint4 u; short8 s; };

#pragma unroll
    for (int s = 0; s < 8; ++s) {
        U a;
        if (s < 4) {
            a.u = make_uint4(0u, 0u, 0u, 0u);
            if (aok) {
                a.u = *(const uint4*)(H2 + (size_t)arow * 64 + (s & 3) * 16 + kq * 4);
                if (TF) {
                    const int cb = (s & 3) * 32 + kq * 8;
                    float4 sa = *(const float4*)(scale + cb);
                    float4 sb = *(const float4*)(scale + cb + 4);
                    float4 ha = *(const float4*)(shift + cb);
                    float4 hb = *(const float4*)(shift + cb + 4);
                    a.u.x = packbf2(fmaxf(bflo(a.u.x) * sa.x + ha.x, 0.f),
                                    fmaxf(bfhi(a.u.x) * sa.y + ha.y, 0.f));
                    a.u.y = packbf2(fmaxf(bflo(a.u.y) * sa.z + ha.z, 0.f),
                                    fmaxf(bfhi(a.u.y) * sa.w + ha.w, 0.f));
                    a.u.z = packbf2(fmaxf(bflo(a.u.z) * sb.x + hb.x, 0.f),
                                    fmaxf(bfhi(a.u.z) * sb.y + hb.y, 0.f));
                    a.u.w = packbf2(fmaxf(bflo(a.u.w) * sb.z + hb.z, 0.f),
                                    fmaxf(bfhi(a.u.w) * sb.w + hb.w, 0.f));
                }
            }
        } else {
            a.u = *(const uint4*)&aggL[wv * 16 + (lane & 15)][(s & 3) * 16 + kq * 4];
        }
#pragma unroll
        for (int c = 0; c < NT; ++c) {
            U b;
            b.u = *(const uint4*)(Wb + ((size_t)(s * NT + c) * 64 + lane) * 4);
            acc[c] = __builtin_amdgcn_mfma_f32_16x16x32_bf16(a.s, b.s, acc[c], 0, 0, 0);
        }
    }

    const int colbase = lane & 15;

    if (LSM) {
        float vb[NT][4];
#pragma unroll
        for (int c = 0; c < NT; ++c) {
            float bv = bias[c * 16 + colbase];
#pragma unroll
            for (int r = 0; r < 4; ++r) vb[c][r] = acc[c][r] + bv;
        }
#pragma unroll
        for (int r = 0; r < 4; ++r) {
            float m = fmaxf(fmaxf(vb[0][r], vb[1][r]), fmaxf(vb[2][r], vb[3][r]));
#pragma unroll
            for (int o = 8; o >= 1; o >>= 1) m = fmaxf(m, __shfl_xor(m, o));
            float ssum = (expf(vb[0][r] - m) + expf(vb[1][r] - m))
                       + (expf(vb[2][r] - m) + expf(vb[3][r] - m));
#pragma unroll
            for (int o = 8; o >= 1; o >>= 1) ssum += __shfl_xor(ssum, o);
            float lg = m + logf(ssum);
            int orow = wrow0 + kq * 4 + r;
            if (orow < N_NODES) {
#pragma unroll
                for (int c = 0; c < NT; ++c)
                    OutF[(size_t)orow * OUTC + c * 16 + colbase] = vb[c][r] - lg;
            }
        }
        return;
    }

#pragma unroll
    for (int c = 0; c < NT; ++c) {
        const int col = c * 16 + colbase;
        const float bv = bias[col];
        float sc = 0.f, qc = 0.f;
#pragma unroll
        for (int r = 0; r < 4; ++r) {
            int orow = wrow0 + kq * 4 + r;
            float v = acc[c][r] + bv;
            if (BF16OUT) {
                float vo = __shfl_xor(v, 1);   // partner channel (pair-lanes share orow)
                if (orow < N_NODES) {
                    if ((colbase & 1) == 0)
                        OutB[(size_t)orow * (OUTC / 2) + (col >> 1)] = packbf2(v, vo);
                    if (STATS) { sc += v; qc += v * v; }
                }
            } else {
                if (orow < N_NODES) {
                    OutF[(size_t)orow * OUTC + col] = v;
                    if (STATS) { sc += v; qc += v * v; }
                }
            }
        }
        if (STATS) {
            sc += __shfl_xor(sc, 16); sc += __shfl_xor(sc, 32);
            qc += __shfl_xor(qc, 16); qc += __shfl_xor(qc, 32);
            if (kq == 0) {
                red[wv][col]        = sc;
                red[wv][OUTC + col] = qc;
            }
        }
    }
    if (STATS) {
        __syncthreads();
        int t = threadIdx.x;
        if (t < 2 * OUTC) {
            float p = red[0][t] + red[1][t] + red[2][t] + red[3][t];
            Ppart[(size_t)blockIdx.x * (2 * OUTC) + t] = p;
        }
    }
}

// ---------------------------------------------------------------- BN reduce (atomic-free)
__global__ void bn_reduce32(const float* __restrict__ Ppart, float* __restrict__ pstage) {
    int t = threadIdx.x;    // 0..255
    float s = 0.f;
    for (int r = blockIdx.x; r < CONVG_N; r += 32)
        s += Ppart[(size_t)r * 256 + t];
    pstage[(size_t)blockIdx.x * 256 + t] = s;
}

__global__ void bn_finalize32(const float* __restrict__ pstage,
                              const float* __restrict__ g, const float* __restrict__ be,
                              float* __restrict__ scale, float* __restrict__ shift) {
    int c = threadIdx.x;   // 0..127
    float s = 0.f, q = 0.f;
    for (int r = 0; r < 32; ++r) {
        s += pstage[(size_t)r * 256 + c];
        q += pstage[(size_t)r * 256 + 128 + c];
    }
    float mean = s * (1.0f / N_NODES);
    float var  = q * (1.0f / N_NODES) - mean * mean;
    float inv  = rsqrtf(var + 1e-5f);
    float sc   = g[c] * inv;
    scale[c] = sc;
    shift[c] = be[c] - mean * sc;
}

// ---------------------------------------------------------------- launch

extern "C" void kernel_launch(void* const* d_in, const int* in_sizes, int n_in,
                              void* d_out, int out_size, void* d_ws, size_t ws_size,
                              hipStream_t stream) {
    const float* x   = (const float*)d_in[0];
    const int*   ei  = (const int*)d_in[1];
    const float* w0s = (const float*)d_in[2];
    const float* w0n = (const float*)d_in[3];
    const float* b0  = (const float*)d_in[4];
    const float* g0  = (const float*)d_in[5];
    const float* be0 = (const float*)d_in[6];
    const float* w1s = (const float*)d_in[7];
    const float* w1n = (const float*)d_in[8];
    const float* b1  = (const float*)d_in[9];
    const float* g1  = (const float*)d_in[10];
    const float* be1 = (const float*)d_in[11];
    const float* w2s = (const float*)d_in[12];
    const float* w2n = (const float*)d_in[13];
    const float* b2  = (const float*)d_in[14];
    float* out = (float*)d_out;

    const int* src = ei;            // edge_index[0]
    const int* dst = ei + N_EDGES;  // edge_index[1]

    char* w = (char*)d_ws;
    size_t off = 0;
    auto alloc = [&](size_t bytes) {
        void* p = w + off;
        off += (bytes + 255) & ~(size_t)255;
        return p;
    };
    int*   deg     = (int*)alloc(N_NODES * 4);
    int*   row_ptr = (int*)alloc((N_NODES + 1) * 4);
    int*   blk     = (int*)alloc(512 * 4);
    int*   colx    = (int*)alloc((size_t)N_EDGES * 4);
    float* invd    = (float*)alloc(N_NODES * 4);
    float* pstage  = (float*)alloc(32 * 256 * 4);
    float* scale0  = (float*)alloc(128 * 4);
    float* shift0  = (float*)alloc(128 * 4);
    float* scale1  = (float*)alloc(128 * 4);
    float* shift1  = (float*)alloc(128 * 4);
    uint*  wb0     = (uint*)alloc(16384 * 4);                  // layer0 packed W
    uint*  wb1     = (uint*)alloc(16384 * 4);                  // layer1 packed W
    uint*  wb2     = (uint*)alloc(8192 * 4);                   // layer2 packed W
    float* ppart   = (float*)alloc((size_t)CONVG_N * 256 * 4); // BN per-block partials
    uint*  ht2     = (uint*)alloc((size_t)N_NODES * 64 * 4);   // packed bf16 x
    uint*  h2a     = (uint*)alloc((size_t)N_NODES * 64 * 4);   // hidden (layer0 out)
    uint*  h2b     = (uint*)alloc((size_t)N_NODES * 64 * 4);   // hidden (layer1 out)
    // rank aliases h2a: rank's last read (fill_csr2) precedes h2a's first write
    // (aggconv layer-0 epilogue).
    int*   rank    = (int*)h2a;

    const int NBk   = NB_SCAN;                    // 391
    const int CONVG = CONVG_N;                    // 1563
    const int PREPG = EB + TFG + 128 + 32;        // 18910

    // fused prep: histogram+rank || x->bf16 || weight repack
    hipMemsetAsync(deg, 0, N_NODES * 4, stream);
    prep_fused<<<PREPG, 256, 0, stream>>>(dst, deg, rank, x, ht2,
                                          w0s, w0n, wb0, w1s, w1n, wb1, w2s, w2n, wb2);
    scan_blocksum<<<NBk, 256, 0, stream>>>(deg, blk);
    scan_blockoff<<<1, 512, 0, stream>>>(blk, row_ptr + N_NODES);
    scan_final<<<NBk, 256, 0, stream>>>(deg, blk, row_ptr, invd);
    fill_csr2<<<EB, 256, 0, stream>>>(src, dst, row_ptr, rank, colx);

    // layer 0: gather+conv fused; ht2 -> h2a (bf16) + stats
    aggconv<128, true, true, false, false><<<CONVG, 256, 0, stream>>>(
        ht2, nullptr, nullptr, row_ptr, colx, invd, wb0, b0, nullptr, h2a, ppart);
    bn_reduce32<<<32, 256, 0, stream>>>(ppart, pstage);
    bn_finalize32<<<1, 128, 0, stream>>>(pstage, g0, be0, scale0, shift0);

    // layer 1: h2a -> h2b (double-buffered: fused gather reads random h2a rows)
    aggconv<128, true, true, true, false><<<CONVG, 256, 0, stream>>>(
        h2a, scale0, shift0, row_ptr, colx, invd, wb1, b1, nullptr, h2b, ppart);
    bn_reduce32<<<32, 256, 0, stream>>>(ppart, pstage);
    bn_finalize32<<<1, 128, 0, stream>>>(pstage, g1, be1, scale1, shift1);

    // layer 2: h2b -> out (fused log_softmax)
    aggconv<64, false, false, true, true><<<CONVG, 256, 0, stream>>>(
        h2b, scale1, shift1, row_ptr, colx, invd, wb2, b2, out, nullptr, nullptr);
}

// Round 14
// 419.012 us; speedup vs baseline: 1.1656x; 1.1656x over previous
//
#include <hip/hip_runtime.h>

typedef unsigned int uint;
typedef __attribute__((ext_vector_type(8))) short short8;   // 8 bf16 (4 VGPRs)
typedef __attribute__((ext_vector_type(4))) float f32x4;    // MFMA accumulator

#define N_NODES 100000
#define N_EDGES 1600000
#define NB_SCAN 391          // ceil(N_NODES/256)
#define CONVG_N 1563         // ceil(N_NODES/64)
#define EB 6250              // ceil(N_EDGES/256)
#define TFG 12500            // ceil(N_NODES*32/256)

// ---------------------------------------------------------------- bf16 helpers
__device__ __forceinline__ float bflo(uint v) { return __uint_as_float(v << 16); }
__device__ __forceinline__ float bfhi(uint v) { return __uint_as_float(v & 0xffff0000u); }
__device__ __forceinline__ uint packbf2(float a, float b) {   // RNE pack (a->lo, b->hi)
    uint ua = __float_as_uint(a), ub = __float_as_uint(b);
    ua += 0x7fffu + ((ua >> 16) & 1u);
    ub += 0x7fffu + ((ub >> 16) & 1u);
    return (ua >> 16) | (ub & 0xffff0000u);
}

// ---------------------------------------------------------------- fused prep
__device__ __forceinline__ void pack_w_body(const float* __restrict__ Wself,
                                            const float* __restrict__ Wneigh,
                                            uint* __restrict__ Wb, int OUTC, int NT, int i) {
    if (i >= 8 * NT * 64 * 4) return;
    int u = i & 3;
    int l = (i >> 2) & 63;
    int t = i >> 8;            // s*NT + c
    int c = t % NT, s = t / NT;
    int k = s * 32 + (l >> 4) * 8 + u * 2;
    int col = c * 16 + (l & 15);
    const float* W0 = (k < 128) ? (Wself + (size_t)k * OUTC)
                                : (Wneigh + (size_t)(k - 128) * OUTC);
    const float* W1 = (k + 1 < 128) ? (Wself + (size_t)(k + 1) * OUTC)
                                    : (Wneigh + (size_t)(k + 1 - 128) * OUTC);
    Wb[i] = packbf2(W0[col], W1[col]);
}

__global__ void prep_fused(const int* __restrict__ dst,
                           int* __restrict__ deg, int* __restrict__ rank,
                           const float* __restrict__ x, uint* __restrict__ ht2,
                           const float* __restrict__ w0s, const float* __restrict__ w0n, uint* __restrict__ wb0,
                           const float* __restrict__ w1s, const float* __restrict__ w1n, uint* __restrict__ wb1,
                           const float* __restrict__ w2s, const float* __restrict__ w2n, uint* __restrict__ wb2) {
    int b = blockIdx.x;
    int tid = threadIdx.x;
    if (b < EB) {
        int e = b * 256 + tid;
        if (e < N_EDGES) rank[e] = atomicAdd(&deg[dst[e]], 1);
    } else if (b < EB + TFG) {
        int i = (b - EB) * 256 + tid;
        if (i < N_NODES * 32) {
            int row = i >> 5, q = i & 31;
            float4 v = *(const float4*)(x + (size_t)row * 128 + q * 4);
            uint2 o;
            o.x = packbf2(v.x, v.y);
            o.y = packbf2(v.z, v.w);
            *(uint2*)(ht2 + (size_t)row * 64 + q * 2) = o;
        }
    } else if (b < EB + TFG + 64) {
        pack_w_body(w0s, w0n, wb0, 128, 8, (b - EB - TFG) * 256 + tid);
    } else if (b < EB + TFG + 128) {
        pack_w_body(w1s, w1n, wb1, 128, 8, (b - EB - TFG - 64) * 256 + tid);
    } else {
        pack_w_body(w2s, w2n, wb2, 64, 4, (b - EB - TFG - 128) * 256 + tid);
    }
}

// ---------------------------------------------------------------- scans
__global__ void scan_blocksum(const int* __restrict__ deg, int* __restrict__ blk) {
    __shared__ int s[256];
    int i = blockIdx.x * 256 + threadIdx.x;
    s[threadIdx.x] = (i < N_NODES) ? deg[i] : 0;
    __syncthreads();
    for (int off = 128; off > 0; off >>= 1) {
        if (threadIdx.x < off) s[threadIdx.x] += s[threadIdx.x + off];
        __syncthreads();
    }
    if (threadIdx.x == 0) blk[blockIdx.x] = s[0];
}

__global__ void scan_blockoff(int* __restrict__ blk, int* __restrict__ row_ptr_last) {
    __shared__ int s[512];
    int t = threadIdx.x;
    int v = (t < NB_SCAN) ? blk[t] : 0;
    s[t] = v;
    __syncthreads();
    for (int off = 1; off < 512; off <<= 1) {
        int xv = (t >= off) ? s[t - off] : 0;
        __syncthreads();
        s[t] += xv;
        __syncthreads();
    }
    if (t < NB_SCAN) blk[t] = s[t] - v;           // exclusive
    if (t == NB_SCAN - 1) *row_ptr_last = s[t];   // total = N_EDGES
}

__global__ void scan_final(const int* __restrict__ deg, const int* __restrict__ blk,
                           int* __restrict__ row_ptr, float* __restrict__ invd) {
    __shared__ int s[256];
    int i = blockIdx.x * 256 + threadIdx.x;
    int v = (i < N_NODES) ? deg[i] : 0;
    s[threadIdx.x] = v;
    __syncthreads();
    for (int off = 1; off < 256; off <<= 1) {
        int xv = (threadIdx.x >= off) ? s[threadIdx.x - off] : 0;
        __syncthreads();
        s[threadIdx.x] += xv;
        __syncthreads();
    }
    if (i < N_NODES) {
        row_ptr[i] = blk[blockIdx.x] + s[threadIdx.x] - v;
        invd[i] = 1.0f / fmaxf((float)v, 1.0f);
    }
}

__global__ void fill_csr2(const int* __restrict__ src, const int* __restrict__ dst,
                          const int* __restrict__ row_ptr, const int* __restrict__ rank,
                          int* __restrict__ colx) {
    int e = blockIdx.x * blockDim.x + threadIdx.x;
    if (e < N_EDGES) colx[row_ptr[dst[e]] + rank[e]] = src[e];
}

// ---------------------------------------------------------------- aggregation
// one wave per node; lane holds channels (2*lane, 2*lane+1) packed.
// unroll-16 first (mean deg = 16): doubles outstanding loads per wave vs
// unroll-8 — tests whether the gather is latency-bound or at the L3/fabric
// service ceiling. TF: relu(v*scale+shift) on the fly.
template <bool TF>
__global__ void aggregate_bf16(const uint* __restrict__ H2,
                               const float* __restrict__ scale, const float* __restrict__ shift,
                               const int* __restrict__ row_ptr, const int* __restrict__ colx,
                               const float* __restrict__ invd, uint* __restrict__ agg2) {
    int lane = threadIdx.x & 63;
    int node = blockIdx.x * 4 + (threadIdx.x >> 6);
    if (node >= N_NODES) return;
    int beg = row_ptr[node], end = row_ptr[node + 1];
    float sc0 = 0.f, sc1 = 0.f, sh0 = 0.f, sh1 = 0.f;
    if (TF) {
        sc0 = scale[2 * lane];     sc1 = scale[2 * lane + 1];
        sh0 = shift[2 * lane];     sh1 = shift[2 * lane + 1];
    }
    float a0 = 0.f, a1 = 0.f;
    int j = beg;
#define ACC1(v)                                                        \
    if (TF) {                                                          \
        a0 += fmaxf(bflo(v) * sc0 + sh0, 0.f);                         \
        a1 += fmaxf(bfhi(v) * sc1 + sh1, 0.f);                         \
    } else {                                                           \
        a0 += bflo(v);                                                 \
        a1 += bfhi(v);                                                 \
    }
    for (; j + 16 <= end; j += 16) {
        int s0 = colx[j],      s1 = colx[j + 1],  s2 = colx[j + 2],  s3 = colx[j + 3];
        int s4 = colx[j + 4],  s5 = colx[j + 5],  s6 = colx[j + 6],  s7 = colx[j + 7];
        int s8 = colx[j + 8],  s9 = colx[j + 9],  sa = colx[j + 10], sb = colx[j + 11];
        int sc = colx[j + 12], sd = colx[j + 13], se = colx[j + 14], sf = colx[j + 15];
        uint v0 = H2[(size_t)s0 * 64 + lane];
        uint v1 = H2[(size_t)s1 * 64 + lane];
        uint v2 = H2[(size_t)s2 * 64 + lane];
        uint v3 = H2[(size_t)s3 * 64 + lane];
        uint v4 = H2[(size_t)s4 * 64 + lane];
        uint v5 = H2[(size_t)s5 * 64 + lane];
        uint v6 = H2[(size_t)s6 * 64 + lane];
        uint v7 = H2[(size_t)s7 * 64 + lane];
        uint v8 = H2[(size_t)s8 * 64 + lane];
        uint v9 = H2[(size_t)s9 * 64 + lane];
        uint va = H2[(size_t)sa * 64 + lane];
        uint vb = H2[(size_t)sb * 64 + lane];
        uint vc = H2[(size_t)sc * 64 + lane];
        uint vd = H2[(size_t)sd * 64 + lane];
        uint ve = H2[(size_t)se * 64 + lane];
        uint vf = H2[(size_t)sf * 64 + lane];
        ACC1(v0) ACC1(v1) ACC1(v2) ACC1(v3) ACC1(v4) ACC1(v5) ACC1(v6) ACC1(v7)
        ACC1(v8) ACC1(v9) ACC1(va) ACC1(vb) ACC1(vc) ACC1(vd) ACC1(ve) ACC1(vf)
    }
    for (; j + 8 <= end; j += 8) {
        int s0 = colx[j],     s1 = colx[j + 1], s2 = colx[j + 2], s3 = colx[j + 3];
        int s4 = colx[j + 4], s5 = colx[j + 5], s6 = colx[j + 6], s7 = colx[j + 7];
        uint v0 = H2[(size_t)s0 * 64 + lane];
        uint v1 = H2[(size_t)s1 * 64 + lane];
        uint v2 = H2[(size_t)s2 * 64 + lane];
        uint v3 = H2[(size_t)s3 * 64 + lane];
        uint v4 = H2[(size_t)s4 * 64 + lane];
        uint v5 = H2[(size_t)s5 * 64 + lane];
        uint v6 = H2[(size_t)s6 * 64 + lane];
        uint v7 = H2[(size_t)s7 * 64 + lane];
        ACC1(v0) ACC1(v1) ACC1(v2) ACC1(v3) ACC1(v4) ACC1(v5) ACC1(v6) ACC1(v7)
    }
    for (; j + 4 <= end; j += 4) {
        int s0 = colx[j], s1 = colx[j + 1], s2 = colx[j + 2], s3 = colx[j + 3];
        uint v0 = H2[(size_t)s0 * 64 + lane];
        uint v1 = H2[(size_t)s1 * 64 + lane];
        uint v2 = H2[(size_t)s2 * 64 + lane];
        uint v3 = H2[(size_t)s3 * 64 + lane];
        ACC1(v0) ACC1(v1) ACC1(v2) ACC1(v3)
    }
    for (; j < end; ++j) {
        uint v = H2[(size_t)colx[j] * 64 + lane];
        ACC1(v)
    }
#undef ACC1
    float id = invd[node];
    agg2[(size_t)node * 64 + lane] = packbf2(a0 * id, a1 * id);
}

// ---------------------------------------------------------------- MFMA conv
template <int OUTC, bool STATS, bool BF16OUT, bool TF, bool LSM>
__global__ __launch_bounds__(256) void conv_mfma(
    const uint* __restrict__ Aself2, const uint* __restrict__ Agg2,
    const uint* __restrict__ Wb, const float* __restrict__ bias,
    const float* __restrict__ scale, const float* __restrict__ shift,
    float* __restrict__ OutF, uint* __restrict__ OutB, float* __restrict__ Ppart) {
    constexpr int NT = OUTC / 16;
    __shared__ float red[4][2 * OUTC];
    const int lane = threadIdx.x & 63;
    const int wv   = threadIdx.x >> 6;
    const int row0 = blockIdx.x * 64 + wv * 16;
    const int arow = row0 + (lane & 15);
    const bool aok = arow < N_NODES;
    const int kq   = lane >> 4;      // 0..3

    f32x4 acc[NT];
#pragma unroll
    for (int c = 0; c < NT; ++c) acc[c] = (f32x4){0.f, 0.f, 0.f, 0.f};

    union U { uint4 u; short8 s; };

#pragma unroll
    for (int s = 0; s < 8; ++s) {
        const uint* Asrc = (s < 4) ? Aself2 : Agg2;
        U a;
        a.u = make_uint4(0u, 0u, 0u, 0u);
        if (aok) {
            a.u = *(const uint4*)(Asrc + (size_t)arow * 64 + (s & 3) * 16 + kq * 4);
            if (TF && s < 4) {
                const int cb = (s & 3) * 32 + kq * 8;
                float4 sa = *(const float4*)(scale + cb);
                float4 sb = *(const float4*)(scale + cb + 4);
                float4 ha = *(const float4*)(shift + cb);
                float4 hb = *(const float4*)(shift + cb + 4);
                a.u.x = packbf2(fmaxf(bflo(a.u.x) * sa.x + ha.x, 0.f),
                                fmaxf(bfhi(a.u.x) * sa.y + ha.y, 0.f));
                a.u.y = packbf2(fmaxf(bflo(a.u.y) * sa.z + ha.z, 0.f),
                                fmaxf(bfhi(a.u.y) * sa.w + ha.w, 0.f));
                a.u.z = packbf2(fmaxf(bflo(a.u.z) * sb.x + hb.x, 0.f),
                                fmaxf(bfhi(a.u.z) * sb.y + hb.y, 0.f));
                a.u.w = packbf2(fmaxf(bflo(a.u.w) * sb.z + hb.z, 0.f),
                                fmaxf(bfhi(a.u.w) * sb.w + hb.w, 0.f));
            }
        }
#pragma unroll
        for (int c = 0; c < NT; ++c) {
            U b;
            b.u = *(const uint4*)(Wb + ((size_t)(s * NT + c) * 64 + lane) * 4);
            acc[c] = __builtin_amdgcn_mfma_f32_16x16x32_bf16(a.s, b.s, acc[c], 0, 0, 0);
        }
    }

    const int colbase = lane & 15;

    if (LSM) {
        float vb[NT][4];
#pragma unroll
        for (int c = 0; c < NT; ++c) {
            float bv = bias[c * 16 + colbase];
#pragma unroll
            for (int r = 0; r < 4; ++r) vb[c][r] = acc[c][r] + bv;
        }
#pragma unroll
        for (int r = 0; r < 4; ++r) {
            float m = fmaxf(fmaxf(vb[0][r], vb[1][r]), fmaxf(vb[2][r], vb[3][r]));
#pragma unroll
            for (int o = 8; o >= 1; o >>= 1) m = fmaxf(m, __shfl_xor(m, o));
            float ssum = (expf(vb[0][r] - m) + expf(vb[1][r] - m))
                       + (expf(vb[2][r] - m) + expf(vb[3][r] - m));
#pragma unroll
            for (int o = 8; o >= 1; o >>= 1) ssum += __shfl_xor(ssum, o);
            float lg = m + logf(ssum);
            int orow = row0 + kq * 4 + r;
            if (orow < N_NODES) {
#pragma unroll
                for (int c = 0; c < NT; ++c)
                    OutF[(size_t)orow * OUTC + c * 16 + colbase] = vb[c][r] - lg;
            }
        }
        return;
    }

#pragma unroll
    for (int c = 0; c < NT; ++c) {
        const int col = c * 16 + colbase;
        const float bv = bias[col];
        float sc = 0.f, qc = 0.f;
#pragma unroll
        for (int r = 0; r < 4; ++r) {
            int orow = row0 + kq * 4 + r;
            float v = acc[c][r] + bv;
            if (BF16OUT) {
                float vo = __shfl_xor(v, 1);   // partner channel (pair-lanes share orow)
                if (orow < N_NODES) {
                    if ((colbase & 1) == 0)
                        OutB[(size_t)orow * (OUTC / 2) + (col >> 1)] = packbf2(v, vo);
                    if (STATS) { sc += v; qc += v * v; }
                }
            } else {
                if (orow < N_NODES) {
                    OutF[(size_t)orow * OUTC + col] = v;
                    if (STATS) { sc += v; qc += v * v; }
                }
            }
        }
        if (STATS) {
            sc += __shfl_xor(sc, 16); sc += __shfl_xor(sc, 32);
            qc += __shfl_xor(qc, 16); qc += __shfl_xor(qc, 32);
            if (kq == 0) {
                red[wv][col]        = sc;
                red[wv][OUTC + col] = qc;
            }
        }
    }
    if (STATS) {
        __syncthreads();
        int t = threadIdx.x;
        if (t < 2 * OUTC) {
            float p = red[0][t] + red[1][t] + red[2][t] + red[3][t];
            Ppart[(size_t)blockIdx.x * (2 * OUTC) + t] = p;
        }
    }
}

// ---------------------------------------------------------------- BN reduce (atomic-free)
__global__ void bn_reduce32(const float* __restrict__ Ppart, float* __restrict__ pstage) {
    int t = threadIdx.x;    // 0..255
    float s = 0.f;
    for (int r = blockIdx.x; r < CONVG_N; r += 32)
        s += Ppart[(size_t)r * 256 + t];
    pstage[(size_t)blockIdx.x * 256 + t] = s;
}

__global__ void bn_finalize32(const float* __restrict__ pstage,
                              const float* __restrict__ g, const float* __restrict__ be,
                              float* __restrict__ scale, float* __restrict__ shift) {
    int c = threadIdx.x;   // 0..127
    float s = 0.f, q = 0.f;
    for (int r = 0; r < 32; ++r) {
        s += pstage[(size_t)r * 256 + c];
        q += pstage[(size_t)r * 256 + 128 + c];
    }
    float mean = s * (1.0f / N_NODES);
    float var  = q * (1.0f / N_NODES) - mean * mean;
    float inv  = rsqrtf(var + 1e-5f);
    float sc   = g[c] * inv;
    scale[c] = sc;
    shift[c] = be[c] - mean * sc;
}

// ---------------------------------------------------------------- launch

extern "C" void kernel_launch(void* const* d_in, const int* in_sizes, int n_in,
                              void* d_out, int out_size, void* d_ws, size_t ws_size,
                              hipStream_t stream) {
    const float* x   = (const float*)d_in[0];
    const int*   ei  = (const int*)d_in[1];
    const float* w0s = (const float*)d_in[2];
    const float* w0n = (const float*)d_in[3];
    const float* b0  = (const float*)d_in[4];
    const float* g0  = (const float*)d_in[5];
    const float* be0 = (const float*)d_in[6];
    const float* w1s = (const float*)d_in[7];
    const float* w1n = (const float*)d_in[8];
    const float* b1  = (const float*)d_in[9];
    const float* g1  = (const float*)d_in[10];
    const float* be1 = (const float*)d_in[11];
    const float* w2s = (const float*)d_in[12];
    const float* w2n = (const float*)d_in[13];
    const float* b2  = (const float*)d_in[14];
    float* out = (float*)d_out;

    const int* src = ei;            // edge_index[0]
    const int* dst = ei + N_EDGES;  // edge_index[1]

    char* w = (char*)d_ws;
    size_t off = 0;
    auto alloc = [&](size_t bytes) {
        void* p = w + off;
        off += (bytes + 255) & ~(size_t)255;
        return p;
    };
    int*   deg     = (int*)alloc(N_NODES * 4);
    int*   row_ptr = (int*)alloc((N_NODES + 1) * 4);
    int*   blk     = (int*)alloc(512 * 4);
    int*   colx    = (int*)alloc((size_t)N_EDGES * 4);
    float* invd    = (float*)alloc(N_NODES * 4);
    float* pstage  = (float*)alloc(32 * 256 * 4);
    float* scale0  = (float*)alloc(128 * 4);
    float* shift0  = (float*)alloc(128 * 4);
    float* scale1  = (float*)alloc(128 * 4);
    float* shift1  = (float*)alloc(128 * 4);
    uint*  wb0     = (uint*)alloc(16384 * 4);                  // layer0 packed W
    uint*  wb1     = (uint*)alloc(16384 * 4);                  // layer1 packed W
    uint*  wb2     = (uint*)alloc(8192 * 4);                   // layer2 packed W
    float* ppart   = (float*)alloc((size_t)CONVG_N * 256 * 4); // BN per-block partials
    uint*  ht2     = (uint*)alloc((size_t)N_NODES * 64 * 4);   // packed bf16 x
    uint*  agg2    = (uint*)alloc((size_t)N_NODES * 64 * 4);   // packed bf16 aggregate
    uint*  h2      = (uint*)alloc((size_t)N_NODES * 64 * 4);   // packed bf16 hidden
    // rank aliases agg2: rank's last read (fill_csr2) precedes agg2's first write.
    int*   rank    = (int*)agg2;

    const int NBk   = NB_SCAN;                    // 391
    const int CONVG = CONVG_N;                    // 1563
    const int AGGG  = (N_NODES + 3) / 4;          // 25000
    const int PREPG = EB + TFG + 128 + 32;        // 18910

    // fused prep: histogram+rank || x->bf16 || weight repack
    hipMemsetAsync(deg, 0, N_NODES * 4, stream);
    prep_fused<<<PREPG, 256, 0, stream>>>(dst, deg, rank, x, ht2,
                                          w0s, w0n, wb0, w1s, w1n, wb1, w2s, w2n, wb2);
    scan_blocksum<<<NBk, 256, 0, stream>>>(deg, blk);
    scan_blockoff<<<1, 512, 0, stream>>>(blk, row_ptr + N_NODES);
    scan_final<<<NBk, 256, 0, stream>>>(deg, blk, row_ptr, invd);
    fill_csr2<<<EB, 256, 0, stream>>>(src, dst, row_ptr, rank, colx);

    // layer 0
    aggregate_bf16<false><<<AGGG, 256, 0, stream>>>(ht2, nullptr, nullptr, row_ptr, colx, invd, agg2);
    conv_mfma<128, true, true, false, false><<<CONVG, 256, 0, stream>>>(
        ht2, agg2, wb0, b0, nullptr, nullptr, nullptr, h2, ppart);
    bn_reduce32<<<32, 256, 0, stream>>>(ppart, pstage);
    bn_finalize32<<<1, 128, 0, stream>>>(pstage, g0, be0, scale0, shift0);

    // layer 1
    aggregate_bf16<true><<<AGGG, 256, 0, stream>>>(h2, scale0, shift0, row_ptr, colx, invd, agg2);
    conv_mfma<128, true, true, true, false><<<CONVG, 256, 0, stream>>>(
        h2, agg2, wb1, b1, scale0, shift0, nullptr, h2, ppart);
    bn_reduce32<<<32, 256, 0, stream>>>(ppart, pstage);
    bn_finalize32<<<1, 128, 0, stream>>>(pstage, g1, be1, scale1, shift1);

    // layer 2: conv + fused log_softmax -> out
    aggregate_bf16<true><<<AGGG, 256, 0, stream>>>(h2, scale1, shift1, row_ptr, colx, invd, agg2);
    conv_mfma<64, false, false, true, true><<<CONVG, 256, 0, stream>>>(
        h2, agg2, wb2, b2, scale1, shift1, out, nullptr, nullptr);
}

// Round 15
// 417.373 us; speedup vs baseline: 1.1702x; 1.0039x over previous
//
#include <hip/hip_runtime.h>

typedef unsigned int uint;
typedef __attribute__((ext_vector_type(8))) short short8;   // 8 bf16 (4 VGPRs)
typedef __attribute__((ext_vector_type(4))) float f32x4;    // MFMA accumulator

#define N_NODES 100000
#define N_EDGES 1600000
#define NB_SCAN 391          // ceil(N_NODES/256)
#define CONVB_N 782          // ceil(N_NODES/128)  (128 rows per block)
#define EB 6250              // ceil(N_EDGES/256)
#define TFG 12500            // ceil(N_NODES*32/256)

// ---------------------------------------------------------------- bf16 helpers
__device__ __forceinline__ float bflo(uint v) { return __uint_as_float(v << 16); }
__device__ __forceinline__ float bfhi(uint v) { return __uint_as_float(v & 0xffff0000u); }
__device__ __forceinline__ uint packbf2(float a, float b) {   // RNE pack (a->lo, b->hi)
    uint ua = __float_as_uint(a), ub = __float_as_uint(b);
    ua += 0x7fffu + ((ua >> 16) & 1u);
    ub += 0x7fffu + ((ub >> 16) & 1u);
    return (ua >> 16) | (ub & 0xffff0000u);
}

// ---------------------------------------------------------------- fused prep
__device__ __forceinline__ void pack_w_body(const float* __restrict__ Wself,
                                            const float* __restrict__ Wneigh,
                                            uint* __restrict__ Wb, int OUTC, int NT, int i) {
    if (i >= 8 * NT * 64 * 4) return;
    int u = i & 3;
    int l = (i >> 2) & 63;
    int t = i >> 8;            // s*NT + c
    int c = t % NT, s = t / NT;
    int k = s * 32 + (l >> 4) * 8 + u * 2;
    int col = c * 16 + (l & 15);
    const float* W0 = (k < 128) ? (Wself + (size_t)k * OUTC)
                                : (Wneigh + (size_t)(k - 128) * OUTC);
    const float* W1 = (k + 1 < 128) ? (Wself + (size_t)(k + 1) * OUTC)
                                    : (Wneigh + (size_t)(k + 1 - 128) * OUTC);
    Wb[i] = packbf2(W0[col], W1[col]);
}

__global__ void prep_fused(const int* __restrict__ dst,
                           int* __restrict__ deg, int* __restrict__ rank,
                           const float* __restrict__ x, uint* __restrict__ ht2,
                           const float* __restrict__ w0s, const float* __restrict__ w0n, uint* __restrict__ wb0,
                           const float* __restrict__ w1s, const float* __restrict__ w1n, uint* __restrict__ wb1,
                           const float* __restrict__ w2s, const float* __restrict__ w2n, uint* __restrict__ wb2) {
    int b = blockIdx.x;
    int tid = threadIdx.x;
    if (b < EB) {
        int e = b * 256 + tid;
        if (e < N_EDGES) rank[e] = atomicAdd(&deg[dst[e]], 1);
    } else if (b < EB + TFG) {
        int i = (b - EB) * 256 + tid;
        if (i < N_NODES * 32) {
            int row = i >> 5, q = i & 31;
            float4 v = *(const float4*)(x + (size_t)row * 128 + q * 4);
            uint2 o;
            o.x = packbf2(v.x, v.y);
            o.y = packbf2(v.z, v.w);
            *(uint2*)(ht2 + (size_t)row * 64 + q * 2) = o;
        }
    } else if (b < EB + TFG + 64) {
        pack_w_body(w0s, w0n, wb0, 128, 8, (b - EB - TFG) * 256 + tid);
    } else if (b < EB + TFG + 128) {
        pack_w_body(w1s, w1n, wb1, 128, 8, (b - EB - TFG - 64) * 256 + tid);
    } else {
        pack_w_body(w2s, w2n, wb2, 64, 4, (b - EB - TFG - 128) * 256 + tid);
    }
}

// ---------------------------------------------------------------- scans
__global__ void scan_blocksum(const int* __restrict__ deg, int* __restrict__ blk) {
    __shared__ int s[256];
    int i = blockIdx.x * 256 + threadIdx.x;
    s[threadIdx.x] = (i < N_NODES) ? deg[i] : 0;
    __syncthreads();
    for (int off = 128; off > 0; off >>= 1) {
        if (threadIdx.x < off) s[threadIdx.x] += s[threadIdx.x + off];
        __syncthreads();
    }
    if (threadIdx.x == 0) blk[blockIdx.x] = s[0];
}

__global__ void scan_blockoff(int* __restrict__ blk, int* __restrict__ row_ptr_last) {
    __shared__ int s[512];
    int t = threadIdx.x;
    int v = (t < NB_SCAN) ? blk[t] : 0;
    s[t] = v;
    __syncthreads();
    for (int off = 1; off < 512; off <<= 1) {
        int xv = (t >= off) ? s[t - off] : 0;
        __syncthreads();
        s[t] += xv;
        __syncthreads();
    }
    if (t < NB_SCAN) blk[t] = s[t] - v;           // exclusive
    if (t == NB_SCAN - 1) *row_ptr_last = s[t];   // total = N_EDGES
}

__global__ void scan_final(const int* __restrict__ deg, const int* __restrict__ blk,
                           int* __restrict__ row_ptr, float* __restrict__ invd) {
    __shared__ int s[256];
    int i = blockIdx.x * 256 + threadIdx.x;
    int v = (i < N_NODES) ? deg[i] : 0;
    s[threadIdx.x] = v;
    __syncthreads();
    for (int off = 1; off < 256; off <<= 1) {
        int xv = (threadIdx.x >= off) ? s[threadIdx.x - off] : 0;
        __syncthreads();
        s[threadIdx.x] += xv;
        __syncthreads();
    }
    if (i < N_NODES) {
        row_ptr[i] = blk[blockIdx.x] + s[threadIdx.x] - v;
        invd[i] = 1.0f / fmaxf((float)v, 1.0f);
    }
}

__global__ void fill_csr2(const int* __restrict__ src, const int* __restrict__ dst,
                          const int* __restrict__ row_ptr, const int* __restrict__ rank,
                          int* __restrict__ colx) {
    int e = blockIdx.x * blockDim.x + threadIdx.x;
    if (e < N_EDGES) colx[row_ptr[dst[e]] + rank[e]] = src[e];
}

// ---------------------------------------------------------------- aggregation
// one wave per node; lane holds channels (2*lane, 2*lane+1) packed.
// unroll-16 (r14: service-bound; unroll adds marginal MLP). TF: fused BN+ReLU.
template <bool TF>
__global__ void aggregate_bf16(const uint* __restrict__ H2,
                               const float* __restrict__ scale, const float* __restrict__ shift,
                               const int* __restrict__ row_ptr, const int* __restrict__ colx,
                               const float* __restrict__ invd, uint* __restrict__ agg2) {
    int lane = threadIdx.x & 63;
    int node = blockIdx.x * 4 + (threadIdx.x >> 6);
    if (node >= N_NODES) return;
    int beg = row_ptr[node], end = row_ptr[node + 1];
    float sc0 = 0.f, sc1 = 0.f, sh0 = 0.f, sh1 = 0.f;
    if (TF) {
        sc0 = scale[2 * lane];     sc1 = scale[2 * lane + 1];
        sh0 = shift[2 * lane];     sh1 = shift[2 * lane + 1];
    }
    float a0 = 0.f, a1 = 0.f;
    int j = beg;
#define ACC1(v)                                                        \
    if (TF) {                                                          \
        a0 += fmaxf(bflo(v) * sc0 + sh0, 0.f);                         \
        a1 += fmaxf(bfhi(v) * sc1 + sh1, 0.f);                         \
    } else {                                                           \
        a0 += bflo(v);                                                 \
        a1 += bfhi(v);                                                 \
    }
    for (; j + 16 <= end; j += 16) {
        int s0 = colx[j],      s1 = colx[j + 1],  s2 = colx[j + 2],  s3 = colx[j + 3];
        int s4 = colx[j + 4],  s5 = colx[j + 5],  s6 = colx[j + 6],  s7 = colx[j + 7];
        int s8 = colx[j + 8],  s9 = colx[j + 9],  sa = colx[j + 10], sb = colx[j + 11];
        int sc = colx[j + 12], sd = colx[j + 13], se = colx[j + 14], sf = colx[j + 15];
        uint v0 = H2[(size_t)s0 * 64 + lane];
        uint v1 = H2[(size_t)s1 * 64 + lane];
        uint v2 = H2[(size_t)s2 * 64 + lane];
        uint v3 = H2[(size_t)s3 * 64 + lane];
        uint v4 = H2[(size_t)s4 * 64 + lane];
        uint v5 = H2[(size_t)s5 * 64 + lane];
        uint v6 = H2[(size_t)s6 * 64 + lane];
        uint v7 = H2[(size_t)s7 * 64 + lane];
        uint v8 = H2[(size_t)s8 * 64 + lane];
        uint v9 = H2[(size_t)s9 * 64 + lane];
        uint va = H2[(size_t)sa * 64 + lane];
        uint vb = H2[(size_t)sb * 64 + lane];
        uint vc = H2[(size_t)sc * 64 + lane];
        uint vd = H2[(size_t)sd * 64 + lane];
        uint ve = H2[(size_t)se * 64 + lane];
        uint vf = H2[(size_t)sf * 64 + lane];
        ACC1(v0) ACC1(v1) ACC1(v2) ACC1(v3) ACC1(v4) ACC1(v5) ACC1(v6) ACC1(v7)
        ACC1(v8) ACC1(v9) ACC1(va) ACC1(vb) ACC1(vc) ACC1(vd) ACC1(ve) ACC1(vf)
    }
    for (; j + 8 <= end; j += 8) {
        int s0 = colx[j],     s1 = colx[j + 1], s2 = colx[j + 2], s3 = colx[j + 3];
        int s4 = colx[j + 4], s5 = colx[j + 5], s6 = colx[j + 6], s7 = colx[j + 7];
        uint v0 = H2[(size_t)s0 * 64 + lane];
        uint v1 = H2[(size_t)s1 * 64 + lane];
        uint v2 = H2[(size_t)s2 * 64 + lane];
        uint v3 = H2[(size_t)s3 * 64 + lane];
        uint v4 = H2[(size_t)s4 * 64 + lane];
        uint v5 = H2[(size_t)s5 * 64 + lane];
        uint v6 = H2[(size_t)s6 * 64 + lane];
        uint v7 = H2[(size_t)s7 * 64 + lane];
        ACC1(v0) ACC1(v1) ACC1(v2) ACC1(v3) ACC1(v4) ACC1(v5) ACC1(v6) ACC1(v7)
    }
    for (; j + 4 <= end; j += 4) {
        int s0 = colx[j], s1 = colx[j + 1], s2 = colx[j + 2], s3 = colx[j + 3];
        uint v0 = H2[(size_t)s0 * 64 + lane];
        uint v1 = H2[(size_t)s1 * 64 + lane];
        uint v2 = H2[(size_t)s2 * 64 + lane];
        uint v3 = H2[(size_t)s3 * 64 + lane];
        ACC1(v0) ACC1(v1) ACC1(v2) ACC1(v3)
    }
    for (; j < end; ++j) {
        uint v = H2[(size_t)colx[j] * 64 + lane];
        ACC1(v)
    }
#undef ACC1
    float id = invd[node];
    agg2[(size_t)node * 64 + lane] = packbf2(a0 * id, a1 * id);
}

// ---------------------------------------------------------------- MFMA conv
// 32 rows per wave (two 16-row fragments g=0,1 SHARE each B-fragment load ->
// halves per-wave Wb traffic, the conv's dominant L2 stream: 400->200 MB).
// Block = 4 waves = 128 rows.
template <int OUTC, bool STATS, bool BF16OUT, bool TF, bool LSM>
__global__ __launch_bounds__(256) void conv_mfma(
    const uint* __restrict__ Aself2, const uint* __restrict__ Agg2,
    const uint* __restrict__ Wb, const float* __restrict__ bias,
    const float* __restrict__ scale, const float* __restrict__ shift,
    float* __restrict__ OutF, uint* __restrict__ OutB, float* __restrict__ Ppart) {
    constexpr int NT = OUTC / 16;
    __shared__ float red[4][2 * OUTC];
    const int lane = threadIdx.x & 63;
    const int wv   = threadIdx.x >> 6;
    const int row0 = blockIdx.x * 128 + wv * 32;   // 32 rows per wave
    const int kq   = lane >> 4;      // 0..3

    f32x4 acc[2][NT];
#pragma unroll
    for (int g = 0; g < 2; ++g)
#pragma unroll
        for (int c = 0; c < NT; ++c) acc[g][c] = (f32x4){0.f, 0.f, 0.f, 0.f};

    union U { uint4 u; short8 s; };

#pragma unroll
    for (int s = 0; s < 8; ++s) {
        const uint* Asrc = (s < 4) ? Aself2 : Agg2;
        U a[2];
        float4 sa, sb, ha, hb;
        if (TF && s < 4) {
            const int cb = (s & 3) * 32 + kq * 8;
            sa = *(const float4*)(scale + cb);
            sb = *(const float4*)(scale + cb + 4);
            ha = *(const float4*)(shift + cb);
            hb = *(const float4*)(shift + cb + 4);
        }
#pragma unroll
        for (int g = 0; g < 2; ++g) {
            const int arow = row0 + g * 16 + (lane & 15);
            a[g].u = make_uint4(0u, 0u, 0u, 0u);
            if (arow < N_NODES) {
                a[g].u = *(const uint4*)(Asrc + (size_t)arow * 64 + (s & 3) * 16 + kq * 4);
                if (TF && s < 4) {
                    a[g].u.x = packbf2(fmaxf(bflo(a[g].u.x) * sa.x + ha.x, 0.f),
                                       fmaxf(bfhi(a[g].u.x) * sa.y + ha.y, 0.f));
                    a[g].u.y = packbf2(fmaxf(bflo(a[g].u.y) * sa.z + ha.z, 0.f),
                                       fmaxf(bfhi(a[g].u.y) * sa.w + ha.w, 0.f));
                    a[g].u.z = packbf2(fmaxf(bflo(a[g].u.z) * sb.x + hb.x, 0.f),
                                       fmaxf(bfhi(a[g].u.z) * sb.y + hb.y, 0.f));
                    a[g].u.w = packbf2(fmaxf(bflo(a[g].u.w) * sb.z + hb.z, 0.f),
                                       fmaxf(bfhi(a[g].u.w) * sb.w + hb.w, 0.f));
                }
            }
        }
#pragma unroll
        for (int c = 0; c < NT; ++c) {
            U b;
            b.u = *(const uint4*)(Wb + ((size_t)(s * NT + c) * 64 + lane) * 4);
            acc[0][c] = __builtin_amdgcn_mfma_f32_16x16x32_bf16(a[0].s, b.s, acc[0][c], 0, 0, 0);
            acc[1][c] = __builtin_amdgcn_mfma_f32_16x16x32_bf16(a[1].s, b.s, acc[1][c], 0, 0, 0);
        }
    }

    const int colbase = lane & 15;

    if (LSM) {
#pragma unroll
        for (int g = 0; g < 2; ++g) {
            float vb[NT][4];
#pragma unroll
            for (int c = 0; c < NT; ++c) {
                float bv = bias[c * 16 + colbase];
#pragma unroll
                for (int r = 0; r < 4; ++r) vb[c][r] = acc[g][c][r] + bv;
            }
#pragma unroll
            for (int r = 0; r < 4; ++r) {
                float m = fmaxf(fmaxf(vb[0][r], vb[1][r]), fmaxf(vb[2][r], vb[3][r]));
#pragma unroll
                for (int o = 8; o >= 1; o >>= 1) m = fmaxf(m, __shfl_xor(m, o));
                float ssum = (expf(vb[0][r] - m) + expf(vb[1][r] - m))
                           + (expf(vb[2][r] - m) + expf(vb[3][r] - m));
#pragma unroll
                for (int o = 8; o >= 1; o >>= 1) ssum += __shfl_xor(ssum, o);
                float lg = m + logf(ssum);
                int orow = row0 + g * 16 + kq * 4 + r;
                if (orow < N_NODES) {
#pragma unroll
                    for (int c = 0; c < NT; ++c)
                        OutF[(size_t)orow * OUTC + c * 16 + colbase] = vb[c][r] - lg;
                }
            }
        }
        return;
    }

#pragma unroll
    for (int c = 0; c < NT; ++c) {
        const int col = c * 16 + colbase;
        const float bv = bias[col];
        float sc = 0.f, qc = 0.f;
#pragma unroll
        for (int g = 0; g < 2; ++g) {
#pragma unroll
            for (int r = 0; r < 4; ++r) {
                int orow = row0 + g * 16 + kq * 4 + r;
                float v = acc[g][c][r] + bv;
                if (BF16OUT) {
                    float vo = __shfl_xor(v, 1);   // partner channel
                    if (orow < N_NODES) {
                        if ((colbase & 1) == 0)
                            OutB[(size_t)orow * (OUTC / 2) + (col >> 1)] = packbf2(v, vo);
                        if (STATS) { sc += v; qc += v * v; }
                    }
                } else {
                    if (orow < N_NODES) {
                        OutF[(size_t)orow * OUTC + col] = v;
                        if (STATS) { sc += v; qc += v * v; }
                    }
                }
            }
        }
        if (STATS) {
            sc += __shfl_xor(sc, 16); sc += __shfl_xor(sc, 32);
            qc += __shfl_xor(qc, 16); qc += __shfl_xor(qc, 32);
            if (kq == 0) {
                red[wv][col]        = sc;
                red[wv][OUTC + col] = qc;
            }
        }
    }
    if (STATS) {
        __syncthreads();
        int t = threadIdx.x;
        if (t < 2 * OUTC) {
            float p = red[0][t] + red[1][t] + red[2][t] + red[3][t];
            Ppart[(size_t)blockIdx.x * (2 * OUTC) + t] = p;
        }
    }
}

// ---------------------------------------------------------------- BN reduce (atomic-free)
__global__ void bn_reduce32(const float* __restrict__ Ppart, float* __restrict__ pstage) {
    int t = threadIdx.x;    // 0..255
    float s = 0.f;
    for (int r = blockIdx.x; r < CONVB_N; r += 32)
        s += Ppart[(size_t)r * 256 + t];
    pstage[(size_t)blockIdx.x * 256 + t] = s;
}

__global__ void bn_finalize32(const float* __restrict__ pstage,
                              const float* __restrict__ g, const float* __restrict__ be,
                              float* __restrict__ scale, float* __restrict__ shift) {
    int c = threadIdx.x;   // 0..127
    float s = 0.f, q = 0.f;
    for (int r = 0; r < 32; ++r) {
        s += pstage[(size_t)r * 256 + c];
        q += pstage[(size_t)r * 256 + 128 + c];
    }
    float mean = s * (1.0f / N_NODES);
    float var  = q * (1.0f / N_NODES) - mean * mean;
    float inv  = rsqrtf(var + 1e-5f);
    float sc   = g[c] * inv;
    scale[c] = sc;
    shift[c] = be[c] - mean * sc;
}

// ---------------------------------------------------------------- launch

extern "C" void kernel_launch(void* const* d_in, const int* in_sizes, int n_in,
                              void* d_out, int out_size, void* d_ws, size_t ws_size,
                              hipStream_t stream) {
    const float* x   = (const float*)d_in[0];
    const int*   ei  = (const int*)d_in[1];
    const float* w0s = (const float*)d_in[2];
    const float* w0n = (const float*)d_in[3];
    const float* b0  = (const float*)d_in[4];
    const float* g0  = (const float*)d_in[5];
    const float* be0 = (const float*)d_in[6];
    const float* w1s = (const float*)d_in[7];
    const float* w1n = (const float*)d_in[8];
    const float* b1  = (const float*)d_in[9];
    const float* g1  = (const float*)d_in[10];
    const float* be1 = (const float*)d_in[11];
    const float* w2s = (const float*)d_in[12];
    const float* w2n = (const float*)d_in[13];
    const float* b2  = (const float*)d_in[14];
    float* out = (float*)d_out;

    const int* src = ei;            // edge_index[0]
    const int* dst = ei + N_EDGES;  // edge_index[1]

    char* w = (char*)d_ws;
    size_t off = 0;
    auto alloc = [&](size_t bytes) {
        void* p = w + off;
        off += (bytes + 255) & ~(size_t)255;
        return p;
    };
    int*   deg     = (int*)alloc(N_NODES * 4);
    int*   row_ptr = (int*)alloc((N_NODES + 1) * 4);
    int*   blk     = (int*)alloc(512 * 4);
    int*   colx    = (int*)alloc((size_t)N_EDGES * 4);
    float* invd    = (float*)alloc(N_NODES * 4);
    float* pstage  = (float*)alloc(32 * 256 * 4);
    float* scale0  = (float*)alloc(128 * 4);
    float* shift0  = (float*)alloc(128 * 4);
    float* scale1  = (float*)alloc(128 * 4);
    float* shift1  = (float*)alloc(128 * 4);
    uint*  wb0     = (uint*)alloc(16384 * 4);                  // layer0 packed W
    uint*  wb1     = (uint*)alloc(16384 * 4);                  // layer1 packed W
    uint*  wb2     = (uint*)alloc(8192 * 4);                   // layer2 packed W
    float* ppart   = (float*)alloc((size_t)CONVB_N * 256 * 4); // BN per-block partials
    uint*  ht2     = (uint*)alloc((size_t)N_NODES * 64 * 4);   // packed bf16 x
    uint*  agg2    = (uint*)alloc((size_t)N_NODES * 64 * 4);   // packed bf16 aggregate
    uint*  h2      = (uint*)alloc((size_t)N_NODES * 64 * 4);   // packed bf16 hidden
    // rank aliases agg2: rank's last read (fill_csr2) precedes agg2's first write.
    int*   rank    = (int*)agg2;

    const int NBk   = NB_SCAN;                    // 391
    const int CONVG = CONVB_N;                    // 782
    const int AGGG  = (N_NODES + 3) / 4;          // 25000
    const int PREPG = EB + TFG + 128 + 32;        // 18910

    // fused prep: histogram+rank || x->bf16 || weight repack
    hipMemsetAsync(deg, 0, N_NODES * 4, stream);
    prep_fused<<<PREPG, 256, 0, stream>>>(dst, deg, rank, x, ht2,
                                          w0s, w0n, wb0, w1s, w1n, wb1, w2s, w2n, wb2);
    scan_blocksum<<<NBk, 256, 0, stream>>>(deg, blk);
    scan_blockoff<<<1, 512, 0, stream>>>(blk, row_ptr + N_NODES);
    scan_final<<<NBk, 256, 0, stream>>>(deg, blk, row_ptr, invd);
    fill_csr2<<<EB, 256, 0, stream>>>(src, dst, row_ptr, rank, colx);

    // layer 0
    aggregate_bf16<false><<<AGGG, 256, 0, stream>>>(ht2, nullptr, nullptr, row_ptr, colx, invd, agg2);
    conv_mfma<128, true, true, false, false><<<CONVG, 256, 0, stream>>>(
        ht2, agg2, wb0, b0, nullptr, nullptr, nullptr, h2, ppart);
    bn_reduce32<<<32, 256, 0, stream>>>(ppart, pstage);
    bn_finalize32<<<1, 128, 0, stream>>>(pstage, g0, be0, scale0, shift0);

    // layer 1
    aggregate_bf16<true><<<AGGG, 256, 0, stream>>>(h2, scale0, shift0, row_ptr, colx, invd, agg2);
    conv_mfma<128, true, true, true, false><<<CONVG, 256, 0, stream>>>(
        h2, agg2, wb1, b1, scale0, shift0, nullptr, h2, ppart);
    bn_reduce32<<<32, 256, 0, stream>>>(ppart, pstage);
    bn_finalize32<<<1, 128, 0, stream>>>(pstage, g1, be1, scale1, shift1);

    // layer 2: conv + fused log_softmax -> out
    aggregate_bf16<true><<<AGGG, 256, 0, stream>>>(h2, scale1, shift1, row_ptr, colx, invd, agg2);
    conv_mfma<64, false, false, true, true><<<CONVG, 256, 0, stream>>>(
        h2, agg2, wb2, b2, scale1, shift1, out, nullptr, nullptr);
}